// Round 9
// baseline (1019.639 us; speedup 1.0000x reference)
//
#include <hip/hip_runtime.h>
#include <math.h>

#define HDIM 4096
#define ODIM 50257
#define NTHR 256
#define GBLK 2048   // big-GEMV grid (1024 per half)

typedef float f32x4 __attribute__((ext_vector_type(4)));

// ---------- helpers ----------

__device__ __forceinline__ float sigm(float v) { return 1.f / (1.f + expf(-v)); }

__device__ __forceinline__ float dot_row(const float* __restrict__ Wrow,
                                         const f32x4* __restrict__ vs,
                                         int lane) {
    const f32x4* w4 = reinterpret_cast<const f32x4*>(Wrow);
    float acc0 = 0.f, acc1 = 0.f;
#pragma unroll
    for (int t = 0; t < 16; t += 2) {
        f32x4 a0 = __builtin_nontemporal_load(&w4[t * 64 + lane]);
        f32x4 b0 = vs[t * 64 + lane];
        f32x4 a1 = __builtin_nontemporal_load(&w4[(t + 1) * 64 + lane]);
        f32x4 b1 = vs[(t + 1) * 64 + lane];
        acc0 = fmaf(a0.x, b0.x, acc0);
        acc0 = fmaf(a0.y, b0.y, acc0);
        acc0 = fmaf(a0.z, b0.z, acc0);
        acc0 = fmaf(a0.w, b0.w, acc0);
        acc1 = fmaf(a1.x, b1.x, acc1);
        acc1 = fmaf(a1.y, b1.y, acc1);
        acc1 = fmaf(a1.z, b1.z, acc1);
        acc1 = fmaf(a1.w, b1.w, acc1);
    }
    float v = acc0 + acc1;
#pragma unroll
    for (int off = 32; off > 0; off >>= 1) v += __shfl_down(v, off, 64);
    return v;  // valid on lane 0
}

__device__ __forceinline__ void stage_v(f32x4* vs, const float* __restrict__ v) {
    const f32x4* v4 = reinterpret_cast<const f32x4*>(v);
#pragma unroll
    for (int i = 0; i < 4; ++i)
        vs[i * NTHR + threadIdx.x] = v4[i * NTHR + threadIdx.x];
}

__device__ __forceinline__ void lse_absorb(float& m, float& s, float mo, float so) {
    if (mo > m) { s = s * expf(m - mo) + so; m = mo; }
    else        { s += so * expf(mo - m); }
}

__device__ __forceinline__ float ldA(const float* p) {
    return __hip_atomic_load(p, __ATOMIC_RELAXED, __HIP_MEMORY_SCOPE_AGENT);
}
__device__ __forceinline__ void stA(float* p, float v) {
    __hip_atomic_store(p, v, __ATOMIC_RELAXED, __HIP_MEMORY_SCOPE_AGENT);
}

// ---------- K1/K2: dual GEMV with pairwise last-finisher gate fusion ----------
// Low half (blocks 0..1023): gi rows {j, j+H, j+2H} for j in [4b, 4b+4), v=vih.
// High half: same rows of Whh into gh, v=vhh. Pair b's SECOND finisher computes
// the 4 GRU gate outputs h[j] (+ optional relu into actout).
__global__ __launch_bounds__(NTHR) void gemv_gate(
    const float* __restrict__ Wih, const float* __restrict__ vih,
    const float* __restrict__ bih, float* __restrict__ gi,
    const float* __restrict__ Whh, const float* __restrict__ vhh,
    const float* __restrict__ bhh, float* __restrict__ gh,
    const float* __restrict__ hprev, float* __restrict__ hout,
    float* __restrict__ actout, int* __restrict__ flags) {
    __shared__ f32x4 vs[HDIM / 4];
    __shared__ int second;
    const bool hiB = blockIdx.x >= (GBLK / 2);
    stage_v(vs, hiB ? vhh : vih);
    __syncthreads();

    const float* W  = hiB ? Whh : Wih;
    const float* bb = hiB ? bhh : bih;
    float*       o  = hiB ? gh : gi;
    const int b = (int)blockIdx.x & (GBLK / 2 - 1);
    const int tid = threadIdx.x, wid = tid >> 6, lane = tid & 63;
    const int j = b * 4 + wid;                 // this wave's gate index

#pragma unroll
    for (int r = 0; r < 3; ++r) {
        int row = j + r * HDIM;                // r, z, n rows for gate j
        float d = dot_row(&W[(size_t)row * HDIM], vs, lane);
        if (lane == 0) stA(&o[row], d + bb[row]);
    }
    __threadfence();
    __syncthreads();
    if (tid == 0) second = (atomicAdd(&flags[b], 1) == 1);
    __syncthreads();
    if (second && lane == 0) {
        float gir = ldA(&gi[j]),            ghr = ldA(&gh[j]);
        float giz = ldA(&gi[j + HDIM]),     ghz = ldA(&gh[j + HDIM]);
        float gin = ldA(&gi[j + 2 * HDIM]), ghn = ldA(&gh[j + 2 * HDIM]);
        float rr = sigm(gir + ghr);
        float zz = sigm(giz + ghz);
        float nn = tanhf(gin + rr * ghn);
        float h  = (1.f - zz) * nn + zz * hprev[j];
        hout[j] = h;
        if (actout) actout[j] = fmaxf(h, 0.f);
    }
}

// ---------- K3: logits GEMV + per-block online LSE ----------
__global__ __launch_bounds__(NTHR) void gemv_logits_lse(
    const float* __restrict__ W, const float* __restrict__ v,
    const float* __restrict__ bias, float* __restrict__ out,
    float2* __restrict__ pairs) {
    __shared__ f32x4 vs[HDIM / 4];
    __shared__ float smx[4], ssm[4];
    stage_v(vs, v);
    __syncthreads();

    const int b = blockIdx.x;
    const int start = b * 24 + min(b, 1105);   // 50257 = 2048*24 + 1105
    const int cnt   = 24 + (b < 1105 ? 1 : 0);
    const int wid = threadIdx.x >> 6, lane = threadIdx.x & 63;
    const int wq = cnt >> 2, wr = cnt & 3;
    const int woff = wid * wq + min(wid, wr);
    const int wcnt = wq + (wid < wr ? 1 : 0);

    float m = -INFINITY, s = 0.f;
    for (int r = 0; r < wcnt; ++r) {
        int row = start + woff + r;
        float d = dot_row(&W[(size_t)row * HDIM], vs, lane);
        if (lane == 0) {
            float val = d + bias[row];
            out[row] = val;
            if (val > m) { s = s * expf(m - val) + 1.f; m = val; }
            else         { s += expf(val - m); }
        }
    }
    if (lane == 0) { smx[wid] = m; ssm[wid] = s; }
    __syncthreads();
    if (threadIdx.x == 0) {
        float M = smx[0], S = ssm[0];
#pragma unroll
        for (int i = 1; i < 4; ++i) lse_absorb(M, S, smx[i], ssm[i]);
        pairs[b] = make_float2(M, S);
    }
}

// ---------- K4: reduce pairs -> logC (redundant per block), subtract ----------
__global__ __launch_bounds__(NTHR) void logsm_final(
    float* __restrict__ out, const float2* __restrict__ pairs) {
    __shared__ float smx[4], ssm[4];
    __shared__ float lc;
    float m = -INFINITY, s = 0.f;
    for (int i = threadIdx.x; i < GBLK; i += NTHR) {
        float2 p = pairs[i];
        lse_absorb(m, s, p.x, p.y);
    }
#pragma unroll
    for (int off = 32; off > 0; off >>= 1) {
        float mo = __shfl_down(m, off, 64);
        float so = __shfl_down(s, off, 64);
        lse_absorb(m, s, mo, so);
    }
    const int wid = threadIdx.x >> 6, lane = threadIdx.x & 63;
    if (lane == 0) { smx[wid] = m; ssm[wid] = s; }
    __syncthreads();
    if (threadIdx.x == 0) {
        float M = smx[0], S = ssm[0];
#pragma unroll
        for (int i = 1; i < 4; ++i) lse_absorb(M, S, smx[i], ssm[i]);
        lc = M + logf(S);
    }
    __syncthreads();
    float logC = lc;
    for (int i = blockIdx.x * NTHR + threadIdx.x; i < ODIM; i += gridDim.x * NTHR)
        out[i] -= logC;
}

// ---------- launch ----------

extern "C" void kernel_launch(void* const* d_in, const int* in_sizes, int n_in,
                              void* d_out, int out_size, void* d_ws, size_t ws_size,
                              hipStream_t stream) {
    const float* x     = (const float*)d_in[0];
    const float* h0    = (const float*)d_in[1];
    const float* w_ih1 = (const float*)d_in[2];
    const float* w_hh1 = (const float*)d_in[3];
    const float* b_ih1 = (const float*)d_in[4];
    const float* b_hh1 = (const float*)d_in[5];
    const float* w_ih2 = (const float*)d_in[6];
    const float* w_hh2 = (const float*)d_in[7];
    const float* b_ih2 = (const float*)d_in[8];
    const float* b_hh2 = (const float*)d_in[9];
    const float* w_out = (const float*)d_in[10];
    const float* b_out = (const float*)d_in[11];

    float* out    = (float*)d_out;         // log_softmax [50257]
    float* h2_out = out + ODIM;            // h2 [4096]

    float* ws   = (float*)d_ws;
    float* gi1  = ws;                      // 12288
    float* gh1  = ws + 12288;              // 12288
    float* gi2  = ws + 24576;              // 12288
    float* gh2  = ws + 36864;              // 12288
    float* h1g  = ws + 49152;              // 4096
    float* act  = ws + 53248;              // 4096
    float2* pairs = (float2*)(ws + 57344); // 2048 float2 -> ends at 61440
    int* flag1  = (int*)(ws + 61440);      // 1024
    int* flag2  = (int*)(ws + 62464);      // 1024

    hipMemsetAsync(flag1, 0, 2048 * sizeof(int), stream);  // flag1+flag2

    // K1: layer-1 GEMVs + gate-1 (h1)
    gemv_gate<<<GBLK, NTHR, 0, stream>>>(w_ih1, x, b_ih1, gi1,
                                         w_hh1, h0, b_hh1, gh1,
                                         h0, h1g, nullptr, flag1);
    // K2: layer-2 GEMVs (v = h1, hprev = h1) + gate-2 (h2, act)
    gemv_gate<<<GBLK, NTHR, 0, stream>>>(w_ih2, h1g, b_ih2, gi2,
                                         w_hh2, h1g, b_hh2, gh2,
                                         h1g, h2_out, act, flag2);
    // K3: logits + per-block LSE
    gemv_logits_lse<<<GBLK, NTHR, 0, stream>>>(w_out, act, b_out, out, pairs);
    // K4: finalize log-softmax
    logsm_final<<<64, NTHR, 0, stream>>>(out, pairs);
}

// Round 10
// 265.907 us; speedup vs baseline: 3.8346x; 3.8346x over previous
//
#include <hip/hip_runtime.h>
#include <math.h>

#define HDIM 4096
#define ODIM 50257
#define G3H  12288        // 3*HDIM
#define NBLK 2048         // blocks for the big GEMVs
#define NTHR 256

typedef float f32x4 __attribute__((ext_vector_type(4)));

// ---------- helpers ----------

// dot of one 4096-long W row (global, nontemporal) with v staged in LDS
__device__ __forceinline__ float dot_row(const float* __restrict__ Wrow,
                                         const f32x4* __restrict__ vs,
                                         int lane) {
    const f32x4* w4 = reinterpret_cast<const f32x4*>(Wrow);
    float acc0 = 0.f, acc1 = 0.f;
#pragma unroll
    for (int t = 0; t < 16; t += 2) {
        f32x4 a0 = __builtin_nontemporal_load(&w4[t * 64 + lane]);
        f32x4 b0 = vs[t * 64 + lane];
        f32x4 a1 = __builtin_nontemporal_load(&w4[(t + 1) * 64 + lane]);
        f32x4 b1 = vs[(t + 1) * 64 + lane];
        acc0 = fmaf(a0.x, b0.x, acc0);
        acc0 = fmaf(a0.y, b0.y, acc0);
        acc0 = fmaf(a0.z, b0.z, acc0);
        acc0 = fmaf(a0.w, b0.w, acc0);
        acc1 = fmaf(a1.x, b1.x, acc1);
        acc1 = fmaf(a1.y, b1.y, acc1);
        acc1 = fmaf(a1.z, b1.z, acc1);
        acc1 = fmaf(a1.w, b1.w, acc1);
    }
    float v = acc0 + acc1;
#pragma unroll
    for (int off = 32; off > 0; off >>= 1) v += __shfl_down(v, off, 64);
    return v;  // valid on lane 0
}

__device__ __forceinline__ void stage_v(f32x4* vs, const float* __restrict__ v) {
    const f32x4* v4 = reinterpret_cast<const f32x4*>(v);
#pragma unroll
    for (int i = 0; i < 4; ++i)
        vs[i * NTHR + threadIdx.x] = v4[i * NTHR + threadIdx.x];
}

__device__ __forceinline__ void lse_absorb(float& m, float& s, float mo, float so) {
    if (mo > m) { s = s * expf(m - mo) + so; m = mo; }
    else        { s += so * expf(mo - m); }
}

// ---------- kernels ----------

// Two independent 12288x4096 GEMVs. Blocks [0,1024) do A, [1024,2048) do B.
// Each block stages its v into LDS and owns 12 contiguous rows (3 per wave).
__global__ __launch_bounds__(NTHR) void gemv_dual(
    const float* __restrict__ Wa, const float* __restrict__ va,
    const float* __restrict__ ba, float* __restrict__ oa,
    const float* __restrict__ Wb, const float* __restrict__ vb,
    const float* __restrict__ bb, float* __restrict__ ob) {
    __shared__ f32x4 vs[HDIM / 4];   // 16 KB
    const bool isB = blockIdx.x >= (NBLK / 2);
    const float* W  = isB ? Wb : Wa;
    const float* v  = isB ? vb : va;
    const float* bs = isB ? bb : ba;
    float*       o  = isB ? ob : oa;
    const int blk = isB ? (int)blockIdx.x - NBLK / 2 : (int)blockIdx.x;

    stage_v(vs, v);
    __syncthreads();

    const int wid = threadIdx.x >> 6, lane = threadIdx.x & 63;
    const int row0 = blk * 12 + wid * 3;
#pragma unroll
    for (int r = 0; r < 3; ++r) {
        int row = row0 + r;
        float d = dot_row(&W[(size_t)row * HDIM], vs, lane);
        if (lane == 0) o[row] = d + bs[row];
    }
}

// GRU gate math: h = (1-z)*n + z*hprev. If act!=nullptr also emits relu(h).
__global__ void gru_gate(const float* __restrict__ gi, const float* __restrict__ gh,
                         const float* __restrict__ hprev, float* __restrict__ hout,
                         float* __restrict__ act) {
    int j = blockIdx.x * blockDim.x + threadIdx.x;
    if (j < HDIM) {
        float r = 1.f / (1.f + expf(-(gi[j] + gh[j])));
        float z = 1.f / (1.f + expf(-(gi[HDIM + j] + gh[HDIM + j])));
        float n = tanhf(gi[2 * HDIM + j] + r * gh[2 * HDIM + j]);
        float h = (1.f - z) * n + z * hprev[j];
        hout[j] = h;
        if (act) act[j] = fmaxf(h, 0.f);
    }
}

// Logits GEMV fused with per-block online log-sum-exp.
// Block b owns rows [b*24 + min(b,1105), +24 or 25); waves sub-split that.
__global__ __launch_bounds__(NTHR) void gemv_logits_lse(
    const float* __restrict__ W, const float* __restrict__ v,
    const float* __restrict__ bias, float* __restrict__ out,
    float2* __restrict__ pairs) {
    __shared__ f32x4 vs[HDIM / 4];   // 16 KB
    __shared__ float smx[4], ssm[4];

    stage_v(vs, v);
    __syncthreads();

    const int b = blockIdx.x;
    const int start = b * 24 + min(b, 1105);
    const int cnt   = 24 + (b < 1105 ? 1 : 0);
    const int wid = threadIdx.x >> 6, lane = threadIdx.x & 63;
    const int wq = cnt >> 2, wr = cnt & 3;
    const int woff = wid * wq + min(wid, wr);
    const int wcnt = wq + (wid < wr ? 1 : 0);

    float m = -INFINITY, s = 0.f;
    for (int r = 0; r < wcnt; ++r) {
        int row = start + woff + r;
        float d = dot_row(&W[(size_t)row * HDIM], vs, lane);
        if (lane == 0) {
            float val = d + bias[row];
            out[row] = val;
            if (val > m) { s = s * expf(m - val) + 1.f; m = val; }
            else         { s += expf(val - m); }
        }
    }
    if (lane == 0) { smx[wid] = m; ssm[wid] = s; }
    __syncthreads();
    if (threadIdx.x == 0) {
        float M = smx[0], S = ssm[0];
#pragma unroll
        for (int i = 1; i < 4; ++i) lse_absorb(M, S, smx[i], ssm[i]);
        pairs[b] = make_float2(M, S);
    }
}

// Every block deterministically reduces the 2048 (m,s) pairs to logC,
// then subtracts over its grid-stride slice of the logits.
__global__ __launch_bounds__(NTHR) void logsm_final(
    float* __restrict__ out, const float2* __restrict__ pairs) {
    __shared__ float smx[4], ssm[4];
    __shared__ float lc;
    float m = -INFINITY, s = 0.f;
    for (int i = threadIdx.x; i < NBLK; i += NTHR) {
        float2 p = pairs[i];
        lse_absorb(m, s, p.x, p.y);
    }
#pragma unroll
    for (int off = 32; off > 0; off >>= 1) {
        float mo = __shfl_down(m, off, 64);
        float so = __shfl_down(s, off, 64);
        lse_absorb(m, s, mo, so);
    }
    const int wid = threadIdx.x >> 6, lane = threadIdx.x & 63;
    if (lane == 0) { smx[wid] = m; ssm[wid] = s; }
    __syncthreads();
    if (threadIdx.x == 0) {
        float M = smx[0], S = ssm[0];
#pragma unroll
        for (int i = 1; i < 4; ++i) lse_absorb(M, S, smx[i], ssm[i]);
        lc = M + logf(S);
    }
    __syncthreads();
    float logC = lc;
    for (int i = blockIdx.x * NTHR + threadIdx.x; i < ODIM; i += gridDim.x * NTHR)
        out[i] -= logC;
}

// ---------- launch ----------

extern "C" void kernel_launch(void* const* d_in, const int* in_sizes, int n_in,
                              void* d_out, int out_size, void* d_ws, size_t ws_size,
                              hipStream_t stream) {
    const float* x     = (const float*)d_in[0];
    const float* h0    = (const float*)d_in[1];
    const float* w_ih1 = (const float*)d_in[2];
    const float* w_hh1 = (const float*)d_in[3];
    const float* b_ih1 = (const float*)d_in[4];
    const float* b_hh1 = (const float*)d_in[5];
    const float* w_ih2 = (const float*)d_in[6];
    const float* w_hh2 = (const float*)d_in[7];
    const float* b_ih2 = (const float*)d_in[8];
    const float* b_hh2 = (const float*)d_in[9];
    const float* w_out = (const float*)d_in[10];
    const float* b_out = (const float*)d_in[11];

    float* out    = (float*)d_out;        // log_softmax [50257]
    float* h2_out = out + ODIM;           // h2 [4096]

    float* ws   = (float*)d_ws;
    float* gi1  = ws;                     // 12288
    float* gh1  = ws + 12288;             // 12288
    float* gi2  = ws + 24576;             // 12288
    float* gh2  = ws + 36864;             // 12288
    float* h1   = ws + 49152;             // 4096
    float* act  = ws + 53248;             // 4096
    float2* pairs = (float2*)(ws + 57344);// 2048 float2

    gemv_dual<<<NBLK, NTHR, 0, stream>>>(w_ih1, x, b_ih1, gi1,
                                         w_hh1, h0, b_hh1, gh1);
    gru_gate<<<HDIM / NTHR, NTHR, 0, stream>>>(gi1, gh1, h0, h1, nullptr);

    gemv_dual<<<NBLK, NTHR, 0, stream>>>(w_ih2, h1, b_ih2, gi2,
                                         w_hh2, h1, b_hh2, gh2);
    gru_gate<<<HDIM / NTHR, NTHR, 0, stream>>>(gi2, gh2, h1, h2_out, act);

    gemv_logits_lse<<<NBLK, NTHR, 0, stream>>>(w_out, act, b_out, out, pairs);
    logsm_final<<<64, NTHR, 0, stream>>>(out, pairs);
}